// Round 1
// baseline (3074.467 us; speedup 1.0000x reference)
//
#include <hip/hip_runtime.h>
#include <stdint.h>

// LBG vector quantization, bit-faithful port of the JAX ref.
// Round 17: base = R16 (best, 3.086 ms). Gather-only changes:
// (a) NBLK for CURR=64: 512->2048, CURR=128: 1024->2048 (TLP; NPW>=256 kept);
// (b) matched-row load queue 4-deep -> 8-deep (2x memory-level parallelism).
// No FP chain touched; integer sums commute => bit-identical trajectory
// (absmax 0.4985352).
// Round 18: identical resubmit — prior bench was an infra failure (container
// failed twice); re-running to recover baseline timing + rocprof counters.

#define NPTS 131072
#define DIMS 64
#define KCB  256

struct LbgState { float dist; float prev; unsigned int done; unsigned int k0, k1; unsigned int pad; };

__device__ __forceinline__ uint32_t rotl32(uint32_t v, int n){ return (v<<n)|(v>>(32-n)); }

// Threefry-2x32, 20 rounds (matches jax._src.prng.threefry2x32)
__device__ __forceinline__ void tf2x32(uint32_t k0, uint32_t k1, uint32_t x0, uint32_t x1,
                                       uint32_t& o0, uint32_t& o1){
  uint32_t ks2 = k0 ^ k1 ^ 0x1BD11BDAu;
  x0 += k0; x1 += k1;
  #define TFR(r) { x0 += x1; x1 = rotl32(x1, r); x1 ^= x0; }
  TFR(13) TFR(15) TFR(26) TFR(6)
  x0 += k1; x1 += ks2 + 1u;
  TFR(17) TFR(29) TFR(16) TFR(24)
  x0 += ks2; x1 += k0 + 2u;
  TFR(13) TFR(15) TFR(26) TFR(6)
  x0 += k0; x1 += k1 + 3u;
  TFR(17) TFR(29) TFR(16) TFR(24)
  x0 += k1; x1 += ks2 + 4u;
  TFR(13) TFR(15) TFR(26) TFR(6)
  x0 += ks2; x1 += k0 + 5u;
  #undef TFR
  o0 = x0; o1 = x1;
}

// XLA ErfInv (f32, Giles polynomial)
__device__ __forceinline__ float xla_erfinv_f32(float x){
  float w = -log1pf(-x*x);
  float p;
  if (w < 5.0f){
    w = w - 2.5f;
    p = 2.81022636e-08f;
    p = fmaf(p, w, 3.43273939e-07f);
    p = fmaf(p, w, -3.5233877e-06f);
    p = fmaf(p, w, -4.39150654e-06f);
    p = fmaf(p, w, 0.00021858087f);
    p = fmaf(p, w, -0.00125372503f);
    p = fmaf(p, w, -0.00417768164f);
    p = fmaf(p, w, 0.246640727f);
    p = fmaf(p, w, 1.50140941f);
  } else {
    w = sqrtf(w) - 3.0f;
    p = -0.000200214257f;
    p = fmaf(p, w, 0.000100950558f);
    p = fmaf(p, w, 0.00134934322f);
    p = fmaf(p, w, -0.00367342844f);
    p = fmaf(p, w, 0.00573950773f);
    p = fmaf(p, w, -0.0076224613f);
    p = fmaf(p, w, 0.00943887047f);
    p = fmaf(p, w, 1.00167406f);
    p = fmaf(p, w, 2.83297682f);
  }
  return p * x;
}

__device__ __forceinline__ float jax_normal_elem(uint32_t k0, uint32_t k1, uint32_t j){
  uint32_t o0, o1; tf2x32(k0, k1, 0u, j, o0, o1);
  uint32_t bits = o0 ^ o1;
  uint32_t fb = (bits >> 9) | 0x3f800000u;
  float f = __uint_as_float(fb) - 1.0f;
  const float lo = -0.99999994f;
  float u = f * 2.0f + lo;
  u = fmaxf(lo, u);
  return 1.41421356f * xla_erfinv_f32(u);
}

// --- split phase (used by mean last-block for split0 and control at n==4) ---
__device__ void do_split(float* __restrict__ cb, float* __restrict__ cnorm,
                         unsigned long long* __restrict__ sums,
                         unsigned int* __restrict__ ndata,
                         unsigned long long* __restrict__ distacc,
                         LbgState* __restrict__ st, int curr, int split, int t){
  __shared__ uint32_t kr0s, kr1s;
  if (t == 0){
    uint32_t ks0, ks1, a0, a1, b0, b1;
    tf2x32(0u, 42u, 0u, (uint32_t)split, ks0, ks1);
    tf2x32(ks0, ks1, 0u, 0u, a0, a1);
    tf2x32(ks0, ks1, 0u, 1u, b0, b1);
    kr0s = a0; kr1s = a1;
    st->k0 = b0; st->k1 = b1;
    st->prev = st->dist;
    st->done = 0u;
  }
  __syncthreads();
  const int n = curr * DIMS;
  for (int e = t; e < n; e += 256){
    int c = e >> 6, d = e & 63;
    float rv = jax_normal_elem(kr0s, kr1s, (uint32_t)e) * 1e-5f;
    float old = cb[c*DIMS + d];
    cb[(curr + c)*DIMS + d] = old - rv;
    cb[c*DIMS + d]          = old + rv;
  }
  __syncthreads();
  const int c2 = curr * 2;
  for (int c = t; c < c2; c += 256){
    float s = 0.f;
    for (int d = 0; d < DIMS; d++){ float vv = cb[c*DIMS+d]; s += vv*vv; }
    cnorm[c] = s;
  }
  for (int e = t; e < c2*DIMS; e += 256) sums[e] = 0ull;
  for (int c = t; c < c2; c += 256) ndata[c] = 0u;
  if (t == 0) *distacc = 0ull;
}

// --- mean of x (LDS-tiled) + last block does init + split0 ---
__global__ void mean_kernel(const float* __restrict__ x, unsigned long long* __restrict__ macc,
                            float* __restrict__ cb, float* __restrict__ cnorm,
                            unsigned long long* __restrict__ sums,
                            unsigned int* __restrict__ ndata,
                            unsigned long long* __restrict__ distacc,
                            LbgState* __restrict__ st, unsigned int* __restrict__ mcnt){
  __shared__ double part[256];
  __shared__ float stage[16*64];
  __shared__ int islast;
  const int t = threadIdx.x;
  const int d = t & 63;
  const int w = t >> 6;
  const size_t base = (size_t)blockIdx.x * 1024;
  const int lrow = t >> 4;
  const int lcol = (t & 15) * 4;

  const float4* xg = reinterpret_cast<const float4*>(x);
  float4 nxt = xg[((base + lrow) * DIMS + lcol) >> 2];
  double s = 0.0;
  for (int tt = 0; tt < 64; tt++){
    float4 cur = nxt;
    if (tt < 63)
      nxt = xg[((base + (tt+1)*16 + lrow) * DIMS + lcol) >> 2];
    __syncthreads();
    *reinterpret_cast<float4*>(&stage[lrow*DIMS + lcol]) = cur;
    __syncthreads();
    s += (double)stage[(w    )*DIMS + d];
    s += (double)stage[(w + 4)*DIMS + d];
    s += (double)stage[(w + 8)*DIMS + d];
    s += (double)stage[(w +12)*DIMS + d];
  }
  part[t] = s;
  __syncthreads();
  if (t < 64){
    double tot = part[t] + part[64+t] + part[128+t] + part[192+t];
    atomicAdd(&macc[t], (unsigned long long)__double2ll_rn(tot * 1099511627776.0));
  }
  __threadfence();
  __syncthreads();
  if (t == 0) islast = (atomicAdd(mcnt, 1u) == (unsigned)(gridDim.x - 1));
  __syncthreads();
  if (!islast) return;

  if (t < 64){
    long long mv = (long long)atomicAdd(&macc[t], 0ull);
    double mean = (double)mv * (1.0/1099511627776.0) / 131072.0;
    cb[t] = (float)mean;
  }
  for (int e = t; e < KCB*DIMS; e += 256)
    if (e >= 64) cb[e] = 1e10f;
  if (t == 0){
    st->dist = __builtin_inff();
    st->prev = __builtin_inff();
    st->done = 0u;
    atomicExch(mcnt, 0u);
  }
  __syncthreads();
  do_split(cb, cnorm, sums, ndata, distacc, st, 1, 0, t);
}

// --- E-step for tiny CURR (2,4): one thread per point ---
template<int CURR>
__global__ __launch_bounds__(256, 4)
void estep_kernel(const float* __restrict__ x, const float* __restrict__ cb,
                  const float* __restrict__ cnorm, unsigned char* __restrict__ bidx8,
                  unsigned long long* __restrict__ distacc, const LbgState* __restrict__ st){
  if (st->done) return;
  const int t = threadIdx.x;
  const int lane = t & 63;
  const int p = blockIdx.x * 256 + t;

  float xv[DIMS];
  const float4* xp = reinterpret_cast<const float4*>(x + (size_t)p * DIMS);
  #pragma unroll
  for (int i = 0; i < 16; i++){
    float4 v = xp[i];
    xv[4*i+0] = v.x; xv[4*i+1] = v.y; xv[4*i+2] = v.z; xv[4*i+3] = v.w;
  }
  float xx = 0.f;
  #pragma unroll
  for (int d = 0; d < DIMS; d++) xx += xv[d] * xv[d];

  constexpr int NJ = (CURR < 4) ? CURR : 4;
  float best = __builtin_inff();
  int bi = 0;
  for (int j0 = 0; j0 < CURR; j0 += NJ){
    const float* crow = cb + (size_t)j0 * DIMS;
    float acc[NJ];
    #pragma unroll
    for (int k = 0; k < NJ; k++) acc[k] = 0.f;
    #pragma unroll
    for (int d = 0; d < DIMS; d++){
      #pragma unroll
      for (int k = 0; k < NJ; k++)
        acc[k] = fmaf(xv[d], crow[k*DIMS + d], acc[k]);
    }
    #pragma unroll
    for (int k = 0; k < NJ; k++){
      float d2 = (xx - 2.0f*acc[k]) + cnorm[j0 + k];
      if (d2 < best){ best = d2; bi = j0 + k; }
    }
  }
  bidx8[p] = (unsigned char)bi;

  double dd = 0.0;
  const float4* cbv = reinterpret_cast<const float4*>(cb + (size_t)bi * DIMS);
  #pragma unroll
  for (int i = 0; i < 16; i++){
    float4 b = cbv[i];
    float df, sq;
    df = xv[4*i+0] - b.x; sq = df*df; dd += (double)sq;
    df = xv[4*i+1] - b.y; sq = df*df; dd += (double)sq;
    df = xv[4*i+2] - b.z; sq = df*df; dd += (double)sq;
    df = xv[4*i+3] - b.w; sq = df*df; dd += (double)sq;
  }
  for (int off = 32; off > 0; off >>= 1) dd += __shfl_down(dd, off);
  if (lane == 0)
    atomicAdd(distacc, (unsigned long long)__double2ll_rn(dd * 4294967296.0));
}

// --- E-step CURR>=8 "scalar-wave" (R16, NJG = min(CPW,16)) ---
template<int CURR>
__global__ __launch_bounds__(256, 4)
void estep_sw(const float* __restrict__ x, const float* __restrict__ cb,
              const float* __restrict__ cnorm, unsigned char* __restrict__ bidx8,
              unsigned long long* __restrict__ distacc, const LbgState* __restrict__ st){
  if (st->done) return;
  constexpr int CPW = CURR / 4;
  constexpr int NJG = (CPW < 16) ? CPW : 16;
  constexpr int NG = CPW / NJG;
  __shared__ float4 xs[16*128];
  __shared__ float sxx[128];
  __shared__ float sbest[4*128];
  __shared__ int   sidx [4*128];
  __shared__ unsigned char sbidx[128];
  const int t = threadIdx.x;
  const int lane = t & 63;
  const int w = __builtin_amdgcn_readfirstlane(t >> 6);
  const int pbase = blockIdx.x * 128;

  {
    const int p = t & 127, h = t >> 7;
    const float4* xg = reinterpret_cast<const float4*>(x) + (size_t)(pbase + p) * 16 + h * 8;
    #pragma unroll
    for (int j = 0; j < 8; j++)
      xs[(h*8 + j)*128 + p] = xg[j];
  }
  __syncthreads();
  if (t < 128){
    float xx = 0.f;
    #pragma unroll
    for (int k4 = 0; k4 < 16; k4++){
      float4 v = xs[k4*128 + t];
      xx = fmaf(v.x, v.x, xx); xx = fmaf(v.y, v.y, xx);
      xx = fmaf(v.z, v.z, xx); xx = fmaf(v.w, v.w, xx);
    }
    sxx[t] = xx;
  }
  __syncthreads();

  const float xx0 = sxx[lane];
  const float xx1 = sxx[64 + lane];
  float best0 = __builtin_inff(), best1 = __builtin_inff();
  int bi0 = 0, bi1 = 0;
  const float4* cbg = reinterpret_cast<const float4*>(cb);
  const int cwbase = w * CPW;

  for (int g = 0; g < NG; g++){
    const int c0 = cwbase + g*NJG;
    float acc0[NJG], acc1[NJG];
    #pragma unroll
    for (int cj = 0; cj < NJG; cj++){ acc0[cj] = 0.f; acc1[cj] = 0.f; }
    for (int k4 = 0; k4 < 16; k4++){
      float4 xf0 = xs[k4*128 + lane];
      float4 xf1 = xs[k4*128 + 64 + lane];
      #pragma unroll
      for (int cj = 0; cj < NJG; cj++){
        float4 cf = cbg[(size_t)(c0 + cj)*16 + k4];   // wave-uniform -> s_load
        acc0[cj] = fmaf(xf0.x, cf.x, acc0[cj]);
        acc0[cj] = fmaf(xf0.y, cf.y, acc0[cj]);
        acc0[cj] = fmaf(xf0.z, cf.z, acc0[cj]);
        acc0[cj] = fmaf(xf0.w, cf.w, acc0[cj]);
        acc1[cj] = fmaf(xf1.x, cf.x, acc1[cj]);
        acc1[cj] = fmaf(xf1.y, cf.y, acc1[cj]);
        acc1[cj] = fmaf(xf1.z, cf.z, acc1[cj]);
        acc1[cj] = fmaf(xf1.w, cf.w, acc1[cj]);
      }
    }
    #pragma unroll
    for (int cj = 0; cj < NJG; cj++){
      float cn = cnorm[c0 + cj];
      float d20 = (xx0 - 2.0f*acc0[cj]) + cn;
      if (d20 < best0){ best0 = d20; bi0 = c0 + cj; }
      float d21 = (xx1 - 2.0f*acc1[cj]) + cn;
      if (d21 < best1){ best1 = d21; bi1 = c0 + cj; }
    }
  }
  sbest[w*128 + lane]      = best0;  sidx[w*128 + lane]      = bi0;
  sbest[w*128 + 64 + lane] = best1;  sidx[w*128 + 64 + lane] = bi1;
  __syncthreads();

  if (t < 128){
    float best = sbest[t];
    int bi = sidx[t];
    #pragma unroll
    for (int ww = 1; ww < 4; ww++){
      float ob = sbest[ww*128 + t];
      int   oi = sidx [ww*128 + t];
      if (ob < best){ best = ob; bi = oi; }
    }
    sbidx[t] = (unsigned char)bi;
    bidx8[pbase + t] = (unsigned char)bi;
    const float4* cbv = cbg + (size_t)bi * 16;
    double dd = 0.0;
    #pragma unroll
    for (int k4 = 0; k4 < 16; k4++){
      float4 xv = xs[k4*128 + t];
      float4 b = cbv[k4];
      float df, sq;
      df = xv.x - b.x; sq = df*df; dd += (double)sq;
      df = xv.y - b.y; sq = df*df; dd += (double)sq;
      df = xv.z - b.z; sq = df*df; dd += (double)sq;
      df = xv.w - b.w; sq = df*df; dd += (double)sq;
    }
    for (int off = 32; off > 0; off >>= 1) dd += __shfl_down(dd, off);
    if ((t & 63) == 0)
      atomicAdd(distacc, (unsigned long long)__double2ll_rn(dd * 4294967296.0));
  }
}

// --- Gather: ballot-harvest with 8-deep load queue ---
template<int CURR, int NBLK>
__global__ __launch_bounds__(256)
void gather_kernel(const float* __restrict__ x, const unsigned char* __restrict__ bidx8,
                   unsigned long long* __restrict__ sums, unsigned int* __restrict__ ndata,
                   const LbgState* __restrict__ st){
  if (st->done) return;
  constexpr int CLOG = __builtin_ctz(CURR);
  constexpr int NCHUNK = NBLK / CURR;
  constexpr int PPC = NPTS / NCHUNK;
  constexpr int NPW = PPC / 4;
  __shared__ long long sacc[4*64];
  __shared__ unsigned int scw[4];
  const int t = threadIdx.x;
  const int lane = t & 63;
  const int w = t >> 6;
  const int c = blockIdx.x & (CURR - 1);
  const int chunk = blockIdx.x >> CLOG;
  const int pbase = chunk * PPC + w * NPW;

  long long acc = 0;
  unsigned int cnt = 0;
  int q0=0,q1=0,q2=0,q3=0,q4=0,q5=0,q6=0,q7=0, qn=0;
  const uint32_t* bp = reinterpret_cast<const uint32_t*>(bidx8 + pbase);
  for (int i = 0; i < NPW; i += 256){
    const uint32_t b4 = bp[(i >> 2) + lane];
    #pragma unroll
    for (int s = 0; s < 4; s++){
      unsigned long long m = __ballot(((b4 >> (8*s)) & 255u) == (unsigned)c);
      cnt += (unsigned int)__popcll(m);
      while (m){
        const int bit = __builtin_ctzll(m);
        m &= m - 1ull;
        const int p = pbase + i + bit*4 + s;
        if      (qn == 0) q0 = p;
        else if (qn == 1) q1 = p;
        else if (qn == 2) q2 = p;
        else if (qn == 3) q3 = p;
        else if (qn == 4) q4 = p;
        else if (qn == 5) q5 = p;
        else if (qn == 6) q6 = p;
        else              q7 = p;
        qn++;
        if (qn == 8){
          const float v0 = x[(size_t)q0 * DIMS + lane];
          const float v1 = x[(size_t)q1 * DIMS + lane];
          const float v2 = x[(size_t)q2 * DIMS + lane];
          const float v3 = x[(size_t)q3 * DIMS + lane];
          const float v4 = x[(size_t)q4 * DIMS + lane];
          const float v5 = x[(size_t)q5 * DIMS + lane];
          const float v6 = x[(size_t)q6 * DIMS + lane];
          const float v7 = x[(size_t)q7 * DIMS + lane];
          acc += (long long)__double2int_rn((double)v0 * 1048576.0);
          acc += (long long)__double2int_rn((double)v1 * 1048576.0);
          acc += (long long)__double2int_rn((double)v2 * 1048576.0);
          acc += (long long)__double2int_rn((double)v3 * 1048576.0);
          acc += (long long)__double2int_rn((double)v4 * 1048576.0);
          acc += (long long)__double2int_rn((double)v5 * 1048576.0);
          acc += (long long)__double2int_rn((double)v6 * 1048576.0);
          acc += (long long)__double2int_rn((double)v7 * 1048576.0);
          qn = 0;
        }
      }
    }
  }
  if (qn > 0){                               // uniform tail flush (qn 1..7)
    const int i1 = (qn > 1) ? q1 : q0;
    const int i2 = (qn > 2) ? q2 : q0;
    const int i3 = (qn > 3) ? q3 : q0;
    const int i4 = (qn > 4) ? q4 : q0;
    const int i5 = (qn > 5) ? q5 : q0;
    const int i6 = (qn > 6) ? q6 : q0;
    const float v0 = x[(size_t)q0 * DIMS + lane];
    const float v1 = x[(size_t)i1 * DIMS + lane];
    const float v2 = x[(size_t)i2 * DIMS + lane];
    const float v3 = x[(size_t)i3 * DIMS + lane];
    const float v4 = x[(size_t)i4 * DIMS + lane];
    const float v5 = x[(size_t)i5 * DIMS + lane];
    const float v6 = x[(size_t)i6 * DIMS + lane];
    acc += (long long)__double2int_rn((double)v0 * 1048576.0);
    if (qn > 1) acc += (long long)__double2int_rn((double)v1 * 1048576.0);
    if (qn > 2) acc += (long long)__double2int_rn((double)v2 * 1048576.0);
    if (qn > 3) acc += (long long)__double2int_rn((double)v3 * 1048576.0);
    if (qn > 4) acc += (long long)__double2int_rn((double)v4 * 1048576.0);
    if (qn > 5) acc += (long long)__double2int_rn((double)v5 * 1048576.0);
    if (qn > 6) acc += (long long)__double2int_rn((double)v6 * 1048576.0);
  }
  sacc[w*64 + lane] = acc;
  if (lane == 0) scw[w] = cnt;
  __syncthreads();
  if (w == 0){
    long long tot = sacc[lane] + sacc[64+lane] + sacc[128+lane] + sacc[192+lane];
    if (tot) atomicAdd(&sums[c*DIMS + lane], (unsigned long long)(tot * 1048576ll));
    if (lane == 0){
      unsigned int ct = scw[0] + scw[1] + scw[2] + scw[3];
      if (ct) atomicAdd(&ndata[c], ct);
    }
  }
}

// --- convergence + M-step finalize + (n==4) split/finalize (one block) ---
__global__ void control_kernel(float* __restrict__ cb, float* __restrict__ cnorm,
                               unsigned long long* __restrict__ sums,
                               unsigned int* __restrict__ ndata,
                               unsigned long long* __restrict__ distacc,
                               LbgState* __restrict__ st, int curr, int n_iter,
                               int next_split){
  __shared__ int s_stop;
  __shared__ unsigned int sdone;
  __shared__ uint32_t sub0, sub1;
  __shared__ float cm[64];
  __shared__ int redv[256];
  __shared__ int redi[256];
  __shared__ int s_m, s_cnt;
  const int t = threadIdx.x;
  if (t == 0) sdone = st->done;
  __syncthreads();
  const unsigned int done0 = sdone;

  if (!done0){
    if (t == 0){
      double dd = (double)(long long)(*distacc) * (1.0/4294967296.0);
      float sf = (float)dd;
      float d_new = sf / 131072.0f;
      float change = fabsf(st->prev - d_new);
      int conv = (n_iter > 0) && (change / (d_new + 1e-16f) < 1e-5f);
      st->dist = d_new;
      if (!conv) st->prev = d_new;
      st->done = conv ? 1u : 0u;
      s_stop = conv;
      if (!conv){
        uint32_t a0, a1, b0, b1;
        tf2x32(st->k0, st->k1, 0u, 0u, a0, a1);
        tf2x32(st->k0, st->k1, 0u, 1u, b0, b1);
        st->k0 = a0; st->k1 = a1;
        sub0 = b0; sub1 = b1;
      }
    }
    __syncthreads();
    if (!s_stop){
      int v = (t < curr) ? (int)ndata[t] : -1;
      redv[t] = v; redi[t] = t;
      __syncthreads();
      for (int s = 128; s > 0; s >>= 1){
        if (t < s){
          if (redv[t+s] > redv[t] || (redv[t+s] == redv[t] && redi[t+s] < redi[t])){
            redv[t] = redv[t+s]; redi[t] = redi[t+s];
          }
        }
        __syncthreads();
      }
      if (t == 0) s_m = redi[0];
      __syncthreads();
      redv[t] = (t < curr && ndata[t] == 0u) ? 1 : 0;
      __syncthreads();
      for (int s = 128; s > 0; s >>= 1){
        if (t < s) redv[t] += redv[t+s];
        __syncthreads();
      }
      if (t == 0) s_cnt = redv[0];
      __syncthreads();
      const int m = s_m;
      const int cntE = s_cnt;

      if (t < 64){
        unsigned int nm_ = ndata[m]; if (nm_ < 1u) nm_ = 1u;
        double cd = (double)(long long)sums[m*DIMS + t] * (1.0/1099511627776.0) / (double)nm_;
        cm[t] = (float)cd;
      }
      __syncthreads();

      const int total = curr * DIMS;
      for (int e = t; e < total; e += 256){
        int c = e >> 6, d = e & 63;
        if (c == m) continue;
        float nv;
        unsigned int nd = ndata[c];
        if (nd >= 1u){
          double cd = (double)(long long)sums[e] * (1.0/1099511627776.0) / (double)nd;
          nv = (float)cd;
        } else {
          float rv = jax_normal_elem(sub0, sub1, (uint32_t)e) * 1e-5f;
          nv = cm[d] - rv;
        }
        cb[e] = nv;
      }
      if (t < 64){
        float add = 0.f;
        if (cntE > 0){
          float acc = 0.f;
          for (int c = 0; c < curr; c++){
            if (ndata[c] == 0u)
              acc += jax_normal_elem(sub0, sub1, (uint32_t)(c*DIMS + t)) * 1e-5f;
          }
          add = acc / fmaxf((float)cntE, 1.0f);
        }
        cb[m*DIMS + t] = cm[t] + add;
      }
      __syncthreads();

      for (int c = t; c < curr; c += 256){
        float s = 0.f;
        for (int d = 0; d < DIMS; d++){ float vv = cb[c*DIMS+d]; s += vv*vv; }
        cnorm[c] = s;
      }
      for (int e = t; e < total; e += 256) sums[e] = 0ull;
      for (int c = t; c < curr; c += 256) ndata[c] = 0u;
      if (t == 0) *distacc = 0ull;
    }
  }
  __syncthreads();
  if (n_iter == 4){
    if (curr < 256){
      do_split(cb, cnorm, sums, ndata, distacc, st, curr, next_split, t);
    } else if (t == 0){
      cb[KCB*DIMS] = st->dist;               // finalize: out[16384] = distance
    }
  }
}

extern "C" void kernel_launch(void* const* d_in, const int* in_sizes, int n_in,
                              void* d_out, int out_size, void* d_ws, size_t ws_size,
                              hipStream_t stream){
  const float* x = (const float*)d_in[0];
  float* cb = (float*)d_out;
  char* ws = (char*)d_ws;
  unsigned long long* sums    = (unsigned long long*)(ws + 0);        // 131072 B
  unsigned long long* macc    = (unsigned long long*)(ws + 131072);   // 512 B
  unsigned long long* distacc = (unsigned long long*)(ws + 131584);   // 8 B
  LbgState* st                = (LbgState*)(ws + 131592);             // 24 B
  unsigned int* ndata         = (unsigned int*)(ws + 131616);         // 1024 B
  float* cnorm                = (float*)(ws + 132640);                // 1024 B
  unsigned char* bidx8        = (unsigned char*)(ws + 133664);        // 131072 B
  unsigned int* mcnt          = (unsigned int*)(ws + 264736);         // 4 B

  hipMemsetAsync(d_ws, 0, 264744, stream);
  mean_kernel<<<128, 256, 0, stream>>>(x, macc, cb, cnorm, sums, ndata, distacc, st, mcnt);

  for (int split = 0; split < 8; split++){
    const int curr = 2 << split;
    for (int n = 0; n < 5; n++){
      switch (curr){
        case 2:   estep_kernel<2>  <<<512,256,0,stream>>>(x,cb,cnorm,bidx8,distacc,st);
                  gather_kernel<2,256>   <<<256, 256,0,stream>>>(x,bidx8,sums,ndata,st); break;
        case 4:   estep_kernel<4>  <<<512,256,0,stream>>>(x,cb,cnorm,bidx8,distacc,st);
                  gather_kernel<4,512>   <<<512, 256,0,stream>>>(x,bidx8,sums,ndata,st); break;
        case 8:   estep_sw<8>    <<<1024,256,0,stream>>>(x,cb,cnorm,bidx8,distacc,st);
                  gather_kernel<8,1024>  <<<1024,256,0,stream>>>(x,bidx8,sums,ndata,st); break;
        case 16:  estep_sw<16>   <<<1024,256,0,stream>>>(x,cb,cnorm,bidx8,distacc,st);
                  gather_kernel<16,2048> <<<2048,256,0,stream>>>(x,bidx8,sums,ndata,st); break;
        case 32:  estep_sw<32>   <<<1024,256,0,stream>>>(x,cb,cnorm,bidx8,distacc,st);
                  gather_kernel<32,2048> <<<2048,256,0,stream>>>(x,bidx8,sums,ndata,st); break;
        case 64:  estep_sw<64>   <<<1024,256,0,stream>>>(x,cb,cnorm,bidx8,distacc,st);
                  gather_kernel<64,2048> <<<2048,256,0,stream>>>(x,bidx8,sums,ndata,st); break;
        case 128: estep_sw<128>  <<<1024,256,0,stream>>>(x,cb,cnorm,bidx8,distacc,st);
                  gather_kernel<128,2048><<<2048,256,0,stream>>>(x,bidx8,sums,ndata,st); break;
        case 256: estep_sw<256>  <<<1024,256,0,stream>>>(x,cb,cnorm,bidx8,distacc,st);
                  gather_kernel<256,2048><<<2048,256,0,stream>>>(x,bidx8,sums,ndata,st); break;
      }
      control_kernel<<<1, 256, 0, stream>>>(cb, cnorm, sums, ndata, distacc, st, curr, n, split+1);
    }
  }
}

// Round 2
// 2721.182 us; speedup vs baseline: 1.1298x; 1.1298x over previous
//
#include <hip/hip_runtime.h>
#include <stdint.h>

// LBG vector quantization, bit-faithful port of the JAX ref.
// R17 base (3.074 ms measured). Round 19:
// (a) control_kernel 1 block -> 16 blocks, row-partitioned; sums/ndata/
//     distacc/st double-buffered on iteration parity so all cross-block
//     reads are from the read-only side. Per-row FP chains unchanged.
// (b) gather matched-row loads 4B/lane -> float4 (16 lanes/row, 4 rows per
//     wave per load instr). Integer fixed-point sums commute => identical.
// Trajectory bit-identical; expect absmax 0.4985352 exactly.

#define NPTS 131072
#define DIMS 64
#define KCB  256
#define NCB  16   // control blocks

struct LbgState { float dist; float prev; unsigned int done; unsigned int k0, k1; unsigned int pad; };

__device__ __forceinline__ uint32_t rotl32(uint32_t v, int n){ return (v<<n)|(v>>(32-n)); }

// Threefry-2x32, 20 rounds (matches jax._src.prng.threefry2x32)
__device__ __forceinline__ void tf2x32(uint32_t k0, uint32_t k1, uint32_t x0, uint32_t x1,
                                       uint32_t& o0, uint32_t& o1){
  uint32_t ks2 = k0 ^ k1 ^ 0x1BD11BDAu;
  x0 += k0; x1 += k1;
  #define TFR(r) { x0 += x1; x1 = rotl32(x1, r); x1 ^= x0; }
  TFR(13) TFR(15) TFR(26) TFR(6)
  x0 += k1; x1 += ks2 + 1u;
  TFR(17) TFR(29) TFR(16) TFR(24)
  x0 += ks2; x1 += k0 + 2u;
  TFR(13) TFR(15) TFR(26) TFR(6)
  x0 += k0; x1 += k1 + 3u;
  TFR(17) TFR(29) TFR(16) TFR(24)
  x0 += k1; x1 += ks2 + 4u;
  TFR(13) TFR(15) TFR(26) TFR(6)
  x0 += ks2; x1 += k0 + 5u;
  #undef TFR
  o0 = x0; o1 = x1;
}

// XLA ErfInv (f32, Giles polynomial)
__device__ __forceinline__ float xla_erfinv_f32(float x){
  float w = -log1pf(-x*x);
  float p;
  if (w < 5.0f){
    w = w - 2.5f;
    p = 2.81022636e-08f;
    p = fmaf(p, w, 3.43273939e-07f);
    p = fmaf(p, w, -3.5233877e-06f);
    p = fmaf(p, w, -4.39150654e-06f);
    p = fmaf(p, w, 0.00021858087f);
    p = fmaf(p, w, -0.00125372503f);
    p = fmaf(p, w, -0.00417768164f);
    p = fmaf(p, w, 0.246640727f);
    p = fmaf(p, w, 1.50140941f);
  } else {
    w = sqrtf(w) - 3.0f;
    p = -0.000200214257f;
    p = fmaf(p, w, 0.000100950558f);
    p = fmaf(p, w, 0.00134934322f);
    p = fmaf(p, w, -0.00367342844f);
    p = fmaf(p, w, 0.00573950773f);
    p = fmaf(p, w, -0.0076224613f);
    p = fmaf(p, w, 0.00943887047f);
    p = fmaf(p, w, 1.00167406f);
    p = fmaf(p, w, 2.83297682f);
  }
  return p * x;
}

__device__ __forceinline__ float jax_normal_elem(uint32_t k0, uint32_t k1, uint32_t j){
  uint32_t o0, o1; tf2x32(k0, k1, 0u, j, o0, o1);
  uint32_t bits = o0 ^ o1;
  uint32_t fb = (bits >> 9) | 0x3f800000u;
  float f = __uint_as_float(fb) - 1.0f;
  const float lo = -0.99999994f;
  float u = f * 2.0f + lo;
  u = fmaxf(lo, u);
  return 1.41421356f * xla_erfinv_f32(u);
}

// --- split phase used by mean last-block for split0 (single-block form) ---
__device__ void do_split(float* __restrict__ cb, float* __restrict__ cnorm,
                         unsigned long long* __restrict__ sums,
                         unsigned int* __restrict__ ndata,
                         unsigned long long* __restrict__ distacc,
                         LbgState* __restrict__ st, int curr, int split, int t){
  __shared__ uint32_t kr0s, kr1s;
  if (t == 0){
    uint32_t ks0, ks1, a0, a1, b0, b1;
    tf2x32(0u, 42u, 0u, (uint32_t)split, ks0, ks1);
    tf2x32(ks0, ks1, 0u, 0u, a0, a1);
    tf2x32(ks0, ks1, 0u, 1u, b0, b1);
    kr0s = a0; kr1s = a1;
    st->k0 = b0; st->k1 = b1;
    st->prev = st->dist;
    st->done = 0u;
  }
  __syncthreads();
  const int n = curr * DIMS;
  for (int e = t; e < n; e += 256){
    int c = e >> 6, d = e & 63;
    float rv = jax_normal_elem(kr0s, kr1s, (uint32_t)e) * 1e-5f;
    float old = cb[c*DIMS + d];
    cb[(curr + c)*DIMS + d] = old - rv;
    cb[c*DIMS + d]          = old + rv;
  }
  __syncthreads();
  const int c2 = curr * 2;
  for (int c = t; c < c2; c += 256){
    float s = 0.f;
    for (int d = 0; d < DIMS; d++){ float vv = cb[c*DIMS+d]; s += vv*vv; }
    cnorm[c] = s;
  }
  for (int e = t; e < c2*DIMS; e += 256) sums[e] = 0ull;
  for (int c = t; c < c2; c += 256) ndata[c] = 0u;
  if (t == 0) *distacc = 0ull;
}

// --- mean of x (LDS-tiled) + last block does init + split0 ---
__global__ void mean_kernel(const float* __restrict__ x, unsigned long long* __restrict__ macc,
                            float* __restrict__ cb, float* __restrict__ cnorm,
                            unsigned long long* __restrict__ sums,
                            unsigned int* __restrict__ ndata,
                            unsigned long long* __restrict__ distacc,
                            LbgState* __restrict__ st, unsigned int* __restrict__ mcnt){
  __shared__ double part[256];
  __shared__ float stage[16*64];
  __shared__ int islast;
  const int t = threadIdx.x;
  const int d = t & 63;
  const int w = t >> 6;
  const size_t base = (size_t)blockIdx.x * 1024;
  const int lrow = t >> 4;
  const int lcol = (t & 15) * 4;

  const float4* xg = reinterpret_cast<const float4*>(x);
  float4 nxt = xg[((base + lrow) * DIMS + lcol) >> 2];
  double s = 0.0;
  for (int tt = 0; tt < 64; tt++){
    float4 cur = nxt;
    if (tt < 63)
      nxt = xg[((base + (tt+1)*16 + lrow) * DIMS + lcol) >> 2];
    __syncthreads();
    *reinterpret_cast<float4*>(&stage[lrow*DIMS + lcol]) = cur;
    __syncthreads();
    s += (double)stage[(w    )*DIMS + d];
    s += (double)stage[(w + 4)*DIMS + d];
    s += (double)stage[(w + 8)*DIMS + d];
    s += (double)stage[(w +12)*DIMS + d];
  }
  part[t] = s;
  __syncthreads();
  if (t < 64){
    double tot = part[t] + part[64+t] + part[128+t] + part[192+t];
    atomicAdd(&macc[t], (unsigned long long)__double2ll_rn(tot * 1099511627776.0));
  }
  __threadfence();
  __syncthreads();
  if (t == 0) islast = (atomicAdd(mcnt, 1u) == (unsigned)(gridDim.x - 1));
  __syncthreads();
  if (!islast) return;

  if (t < 64){
    long long mv = (long long)atomicAdd(&macc[t], 0ull);
    double mean = (double)mv * (1.0/1099511627776.0) / 131072.0;
    cb[t] = (float)mean;
  }
  for (int e = t; e < KCB*DIMS; e += 256)
    if (e >= 64) cb[e] = 1e10f;
  if (t == 0){
    st->dist = __builtin_inff();
    st->prev = __builtin_inff();
    st->done = 0u;
    atomicExch(mcnt, 0u);
  }
  __syncthreads();
  do_split(cb, cnorm, sums, ndata, distacc, st, 1, 0, t);
}

// --- E-step for tiny CURR (2,4): one thread per point ---
template<int CURR>
__global__ __launch_bounds__(256, 4)
void estep_kernel(const float* __restrict__ x, const float* __restrict__ cb,
                  const float* __restrict__ cnorm, unsigned char* __restrict__ bidx8,
                  unsigned long long* __restrict__ distacc, const LbgState* __restrict__ st){
  if (st->done) return;
  const int t = threadIdx.x;
  const int lane = t & 63;
  const int p = blockIdx.x * 256 + t;

  float xv[DIMS];
  const float4* xp = reinterpret_cast<const float4*>(x + (size_t)p * DIMS);
  #pragma unroll
  for (int i = 0; i < 16; i++){
    float4 v = xp[i];
    xv[4*i+0] = v.x; xv[4*i+1] = v.y; xv[4*i+2] = v.z; xv[4*i+3] = v.w;
  }
  float xx = 0.f;
  #pragma unroll
  for (int d = 0; d < DIMS; d++) xx += xv[d] * xv[d];

  constexpr int NJ = (CURR < 4) ? CURR : 4;
  float best = __builtin_inff();
  int bi = 0;
  for (int j0 = 0; j0 < CURR; j0 += NJ){
    const float* crow = cb + (size_t)j0 * DIMS;
    float acc[NJ];
    #pragma unroll
    for (int k = 0; k < NJ; k++) acc[k] = 0.f;
    #pragma unroll
    for (int d = 0; d < DIMS; d++){
      #pragma unroll
      for (int k = 0; k < NJ; k++)
        acc[k] = fmaf(xv[d], crow[k*DIMS + d], acc[k]);
    }
    #pragma unroll
    for (int k = 0; k < NJ; k++){
      float d2 = (xx - 2.0f*acc[k]) + cnorm[j0 + k];
      if (d2 < best){ best = d2; bi = j0 + k; }
    }
  }
  bidx8[p] = (unsigned char)bi;

  double dd = 0.0;
  const float4* cbv = reinterpret_cast<const float4*>(cb + (size_t)bi * DIMS);
  #pragma unroll
  for (int i = 0; i < 16; i++){
    float4 b = cbv[i];
    float df, sq;
    df = xv[4*i+0] - b.x; sq = df*df; dd += (double)sq;
    df = xv[4*i+1] - b.y; sq = df*df; dd += (double)sq;
    df = xv[4*i+2] - b.z; sq = df*df; dd += (double)sq;
    df = xv[4*i+3] - b.w; sq = df*df; dd += (double)sq;
  }
  for (int off = 32; off > 0; off >>= 1) dd += __shfl_down(dd, off);
  if (lane == 0)
    atomicAdd(distacc, (unsigned long long)__double2ll_rn(dd * 4294967296.0));
}

// --- E-step CURR>=8 "scalar-wave" (R16, NJG = min(CPW,16)) ---
template<int CURR>
__global__ __launch_bounds__(256, 4)
void estep_sw(const float* __restrict__ x, const float* __restrict__ cb,
              const float* __restrict__ cnorm, unsigned char* __restrict__ bidx8,
              unsigned long long* __restrict__ distacc, const LbgState* __restrict__ st){
  if (st->done) return;
  constexpr int CPW = CURR / 4;
  constexpr int NJG = (CPW < 16) ? CPW : 16;
  constexpr int NG = CPW / NJG;
  __shared__ float4 xs[16*128];
  __shared__ float sxx[128];
  __shared__ float sbest[4*128];
  __shared__ int   sidx [4*128];
  __shared__ unsigned char sbidx[128];
  const int t = threadIdx.x;
  const int lane = t & 63;
  const int w = __builtin_amdgcn_readfirstlane(t >> 6);
  const int pbase = blockIdx.x * 128;

  {
    const int p = t & 127, h = t >> 7;
    const float4* xg = reinterpret_cast<const float4*>(x) + (size_t)(pbase + p) * 16 + h * 8;
    #pragma unroll
    for (int j = 0; j < 8; j++)
      xs[(h*8 + j)*128 + p] = xg[j];
  }
  __syncthreads();
  if (t < 128){
    float xx = 0.f;
    #pragma unroll
    for (int k4 = 0; k4 < 16; k4++){
      float4 v = xs[k4*128 + t];
      xx = fmaf(v.x, v.x, xx); xx = fmaf(v.y, v.y, xx);
      xx = fmaf(v.z, v.z, xx); xx = fmaf(v.w, v.w, xx);
    }
    sxx[t] = xx;
  }
  __syncthreads();

  const float xx0 = sxx[lane];
  const float xx1 = sxx[64 + lane];
  float best0 = __builtin_inff(), best1 = __builtin_inff();
  int bi0 = 0, bi1 = 0;
  const float4* cbg = reinterpret_cast<const float4*>(cb);
  const int cwbase = w * CPW;

  for (int g = 0; g < NG; g++){
    const int c0 = cwbase + g*NJG;
    float acc0[NJG], acc1[NJG];
    #pragma unroll
    for (int cj = 0; cj < NJG; cj++){ acc0[cj] = 0.f; acc1[cj] = 0.f; }
    for (int k4 = 0; k4 < 16; k4++){
      float4 xf0 = xs[k4*128 + lane];
      float4 xf1 = xs[k4*128 + 64 + lane];
      #pragma unroll
      for (int cj = 0; cj < NJG; cj++){
        float4 cf = cbg[(size_t)(c0 + cj)*16 + k4];   // wave-uniform -> s_load
        acc0[cj] = fmaf(xf0.x, cf.x, acc0[cj]);
        acc0[cj] = fmaf(xf0.y, cf.y, acc0[cj]);
        acc0[cj] = fmaf(xf0.z, cf.z, acc0[cj]);
        acc0[cj] = fmaf(xf0.w, cf.w, acc0[cj]);
        acc1[cj] = fmaf(xf1.x, cf.x, acc1[cj]);
        acc1[cj] = fmaf(xf1.y, cf.y, acc1[cj]);
        acc1[cj] = fmaf(xf1.z, cf.z, acc1[cj]);
        acc1[cj] = fmaf(xf1.w, cf.w, acc1[cj]);
      }
    }
    #pragma unroll
    for (int cj = 0; cj < NJG; cj++){
      float cn = cnorm[c0 + cj];
      float d20 = (xx0 - 2.0f*acc0[cj]) + cn;
      if (d20 < best0){ best0 = d20; bi0 = c0 + cj; }
      float d21 = (xx1 - 2.0f*acc1[cj]) + cn;
      if (d21 < best1){ best1 = d21; bi1 = c0 + cj; }
    }
  }
  sbest[w*128 + lane]      = best0;  sidx[w*128 + lane]      = bi0;
  sbest[w*128 + 64 + lane] = best1;  sidx[w*128 + 64 + lane] = bi1;
  __syncthreads();

  if (t < 128){
    float best = sbest[t];
    int bi = sidx[t];
    #pragma unroll
    for (int ww = 1; ww < 4; ww++){
      float ob = sbest[ww*128 + t];
      int   oi = sidx [ww*128 + t];
      if (ob < best){ best = ob; bi = oi; }
    }
    sbidx[t] = (unsigned char)bi;
    bidx8[pbase + t] = (unsigned char)bi;
    const float4* cbv = cbg + (size_t)bi * 16;
    double dd = 0.0;
    #pragma unroll
    for (int k4 = 0; k4 < 16; k4++){
      float4 xv = xs[k4*128 + t];
      float4 b = cbv[k4];
      float df, sq;
      df = xv.x - b.x; sq = df*df; dd += (double)sq;
      df = xv.y - b.y; sq = df*df; dd += (double)sq;
      df = xv.z - b.z; sq = df*df; dd += (double)sq;
      df = xv.w - b.w; sq = df*df; dd += (double)sq;
    }
    for (int off = 32; off > 0; off >>= 1) dd += __shfl_down(dd, off);
    if ((t & 63) == 0)
      atomicAdd(distacc, (unsigned long long)__double2ll_rn(dd * 4294967296.0));
  }
}

// --- Gather: ballot-harvest, float4 matched-row loads (4 rows/wave/instr) ---
template<int CURR, int NBLK>
__global__ __launch_bounds__(256)
void gather_kernel(const float* __restrict__ x, const unsigned char* __restrict__ bidx8,
                   unsigned long long* __restrict__ sums, unsigned int* __restrict__ ndata,
                   const LbgState* __restrict__ st){
  if (st->done) return;
  constexpr int CLOG = __builtin_ctz(CURR);
  constexpr int NCHUNK = NBLK / CURR;
  constexpr int PPC = NPTS / NCHUNK;
  constexpr int NPW = PPC / 4;
  __shared__ long long sacc[4][64][4];   // [wave][lane][dim-sub]
  __shared__ unsigned int scw[4];
  const int t = threadIdx.x;
  const int lane = t & 63;
  const int w = t >> 6;
  const int c = blockIdx.x & (CURR - 1);
  const int chunk = blockIdx.x >> CLOG;
  const int pbase = chunk * PPC + w * NPW;
  const int sub = lane >> 4;          // row-slot within a 4-row load group
  const int dof = (lane & 15) * 4;    // dim offset handled by this lane

  long long a0 = 0, a1 = 0, a2 = 0, a3 = 0;
  unsigned int cnt = 0;
  int q0=0,q1=0,q2=0,q3=0,q4=0,q5=0,q6=0,q7=0, qn=0;
  const uint32_t* bp = reinterpret_cast<const uint32_t*>(bidx8 + pbase);
  for (int i = 0; i < NPW; i += 256){
    const uint32_t b4 = bp[(i >> 2) + lane];
    #pragma unroll
    for (int s = 0; s < 4; s++){
      unsigned long long m = __ballot(((b4 >> (8*s)) & 255u) == (unsigned)c);
      cnt += (unsigned int)__popcll(m);
      while (m){
        const int bit = __builtin_ctzll(m);
        m &= m - 1ull;
        const int p = pbase + i + bit*4 + s;
        if      (qn == 0) q0 = p;
        else if (qn == 1) q1 = p;
        else if (qn == 2) q2 = p;
        else if (qn == 3) q3 = p;
        else if (qn == 4) q4 = p;
        else if (qn == 5) q5 = p;
        else if (qn == 6) q6 = p;
        else              q7 = p;
        qn++;
        if (qn == 8){
          const int rA = (sub==0)?q0:(sub==1)?q1:(sub==2)?q2:q3;
          const int rB = (sub==0)?q4:(sub==1)?q5:(sub==2)?q6:q7;
          const float4 vA = *reinterpret_cast<const float4*>(x + (size_t)rA * DIMS + dof);
          const float4 vB = *reinterpret_cast<const float4*>(x + (size_t)rB * DIMS + dof);
          a0 += (long long)__double2int_rn((double)vA.x * 1048576.0);
          a1 += (long long)__double2int_rn((double)vA.y * 1048576.0);
          a2 += (long long)__double2int_rn((double)vA.z * 1048576.0);
          a3 += (long long)__double2int_rn((double)vA.w * 1048576.0);
          a0 += (long long)__double2int_rn((double)vB.x * 1048576.0);
          a1 += (long long)__double2int_rn((double)vB.y * 1048576.0);
          a2 += (long long)__double2int_rn((double)vB.z * 1048576.0);
          a3 += (long long)__double2int_rn((double)vB.w * 1048576.0);
          qn = 0;
        }
      }
    }
  }
  if (qn > 0){                               // tail flush (qn 1..7), q0-padded
    const int i1 = (qn > 1) ? q1 : q0;
    const int i2 = (qn > 2) ? q2 : q0;
    const int i3 = (qn > 3) ? q3 : q0;
    const int i4 = (qn > 4) ? q4 : q0;
    const int i5 = (qn > 5) ? q5 : q0;
    const int i6 = (qn > 6) ? q6 : q0;
    const int rA = (sub==0)?q0:(sub==1)?i1:(sub==2)?i2:i3;
    const int rB = (sub==0)?i4:(sub==1)?i5:(sub==2)?i6:q0;
    const float4 vA = *reinterpret_cast<const float4*>(x + (size_t)rA * DIMS + dof);
    const float4 vB = *reinterpret_cast<const float4*>(x + (size_t)rB * DIMS + dof);
    if (sub < qn){
      a0 += (long long)__double2int_rn((double)vA.x * 1048576.0);
      a1 += (long long)__double2int_rn((double)vA.y * 1048576.0);
      a2 += (long long)__double2int_rn((double)vA.z * 1048576.0);
      a3 += (long long)__double2int_rn((double)vA.w * 1048576.0);
    }
    if (sub + 4 < qn){
      a0 += (long long)__double2int_rn((double)vB.x * 1048576.0);
      a1 += (long long)__double2int_rn((double)vB.y * 1048576.0);
      a2 += (long long)__double2int_rn((double)vB.z * 1048576.0);
      a3 += (long long)__double2int_rn((double)vB.w * 1048576.0);
    }
  }
  sacc[w][lane][0] = a0; sacc[w][lane][1] = a1;
  sacc[w][lane][2] = a2; sacc[w][lane][3] = a3;
  if (lane == 0) scw[w] = cnt;
  __syncthreads();
  if (w == 0){
    // dim d = lane: contributions live at lanes r*16 + (d>>2), slot d&3
    long long tot = 0;
    #pragma unroll
    for (int ww = 0; ww < 4; ww++)
      #pragma unroll
      for (int r = 0; r < 4; r++)
        tot += sacc[ww][r*16 + (lane >> 2)][lane & 3];
    if (tot) atomicAdd(&sums[c*DIMS + lane], (unsigned long long)(tot * 1048576ll));
    if (lane == 0){
      unsigned int ct = scw[0] + scw[1] + scw[2] + scw[3];
      if (ct) atomicAdd(&ndata[c], ct);
    }
  }
}

// --- control: convergence + M-step + (n==4) split/finalize.
// NCB blocks, row-partitioned; reads *_in (parity g), writes *_out (parity g^1).
__global__ void control_kernel(float* __restrict__ cb, float* __restrict__ cnorm,
                               const unsigned long long* __restrict__ sums_in,
                               unsigned long long* __restrict__ sums_out,
                               const unsigned int* __restrict__ ndata_in,
                               unsigned int* __restrict__ ndata_out,
                               const unsigned long long* __restrict__ distacc_in,
                               unsigned long long* __restrict__ distacc_out,
                               const LbgState* __restrict__ st_in,
                               LbgState* __restrict__ st_out,
                               int curr, int n_iter, int next_split){
  __shared__ float cm[64];
  __shared__ int redv[256];
  __shared__ int redi[256];
  __shared__ int s_m, s_cnt;
  const int t = threadIdx.x;
  const int b = blockIdx.x;

  const unsigned int done0 = st_in->done;
  float d_new = 0.f;
  int stop = 1;
  uint32_t sub0 = 0, sub1 = 0, nk0 = 0, nk1 = 0;
  if (!done0){
    double ddv = (double)(long long)(*distacc_in) * (1.0/4294967296.0);
    float sf = (float)ddv;
    d_new = sf / 131072.0f;
    float change = fabsf(st_in->prev - d_new);
    int conv = (n_iter > 0) && (change / (d_new + 1e-16f) < 1e-5f);
    stop = conv;
    if (!conv){
      tf2x32(st_in->k0, st_in->k1, 0u, 0u, nk0, nk1);
      tf2x32(st_in->k0, st_in->k1, 0u, 1u, sub0, sub1);
    }
  }

  const int rpb = (curr + NCB - 1) / NCB;
  const int r0 = b * rpb;
  int r1 = r0 + rpb; if (r1 > curr) r1 = curr;

  if (!done0 && !stop){
    // argmax ndata (tie -> lowest idx) and empty count, redundant per block
    int v = (t < curr) ? (int)ndata_in[t] : -1;
    redv[t] = v; redi[t] = t;
    __syncthreads();
    for (int s = 128; s > 0; s >>= 1){
      if (t < s){
        if (redv[t+s] > redv[t] || (redv[t+s] == redv[t] && redi[t+s] < redi[t])){
          redv[t] = redv[t+s]; redi[t] = redi[t+s];
        }
      }
      __syncthreads();
    }
    if (t == 0) s_m = redi[0];
    __syncthreads();
    redv[t] = (t < curr && ndata_in[t] == 0u) ? 1 : 0;
    __syncthreads();
    for (int s = 128; s > 0; s >>= 1){
      if (t < s) redv[t] += redv[t+s];
      __syncthreads();
    }
    if (t == 0) s_cnt = redv[0];
    __syncthreads();
    const int m = s_m;
    const int cntE = s_cnt;

    if (t < 64){
      unsigned int nm_ = ndata_in[m]; if (nm_ < 1u) nm_ = 1u;
      double cd = (double)(long long)sums_in[m*DIMS + t] * (1.0/1099511627776.0) / (double)nm_;
      cm[t] = (float)cd;
    }
    __syncthreads();

    for (int e = r0*DIMS + t; e < r1*DIMS; e += 256){
      int cc = e >> 6, d = e & 63;
      if (cc == m) continue;
      float nv;
      unsigned int nd = ndata_in[cc];
      if (nd >= 1u){
        double cd = (double)(long long)sums_in[e] * (1.0/1099511627776.0) / (double)nd;
        nv = (float)cd;
      } else {
        float rv = jax_normal_elem(sub0, sub1, (uint32_t)e) * 1e-5f;
        nv = cm[d] - rv;
      }
      cb[e] = nv;
    }
    if (m >= r0 && m < r1 && t < 64){
      float add = 0.f;
      if (cntE > 0){
        float acc = 0.f;
        for (int cc = 0; cc < curr; cc++){
          if (ndata_in[cc] == 0u)
            acc += jax_normal_elem(sub0, sub1, (uint32_t)(cc*DIMS + t)) * 1e-5f;
        }
        add = acc / fmaxf((float)cntE, 1.0f);
      }
      cb[m*DIMS + t] = cm[t] + add;
    }
    __syncthreads();

    for (int cc = r0 + t; cc < r1; cc += 256){
      float s = 0.f;
      for (int d = 0; d < DIMS; d++){ float vv = cb[cc*DIMS+d]; s += vv*vv; }
      cnorm[cc] = s;
    }
  }

  // zero next-parity accumulators (always safe: old contents never needed)
  const int rows_next = (n_iter == 4 && curr < KCB) ? 2*curr : curr;
  for (int e = b*256 + t; e < rows_next*DIMS; e += NCB*256) sums_out[e] = 0ull;
  for (int cc = b*256 + t; cc < rows_next; cc += NCB*256) ndata_out[cc] = 0u;
  if (b == 0 && t == 0) *distacc_out = 0ull;

  // commit state (block 0 only; reads are from st_in, writes to st_out)
  if (b == 0 && t == 0){
    const float fin_dist = done0 ? st_in->dist : d_new;
    LbgState ns;
    ns.dist = fin_dist;
    if (done0 || stop){
      ns.prev = st_in->prev; ns.done = 1u; ns.k0 = st_in->k0; ns.k1 = st_in->k1;
    } else {
      ns.prev = d_new; ns.done = 0u; ns.k0 = nk0; ns.k1 = nk1;
    }
    ns.pad = 0u;
    if (n_iter == 4){
      if (curr < KCB){
        uint32_t ks0, ks1, sa0, sa1, sb0, sb1;
        tf2x32(0u, 42u, 0u, (uint32_t)next_split, ks0, ks1);
        tf2x32(ks0, ks1, 0u, 0u, sa0, sa1);
        tf2x32(ks0, ks1, 0u, 1u, sb0, sb1);
        ns.k0 = sb0; ns.k1 = sb1;
        ns.prev = fin_dist;
        ns.done = 0u;
      } else {
        cb[KCB*DIMS] = fin_dist;               // finalize: out[16384] = distance
      }
    }
    *st_out = ns;
  }

  // split phase (rows partitioned identically -> all cb deps are block-local)
  if (n_iter == 4 && curr < KCB){
    uint32_t ks0, ks1, kr0, kr1, t0, t1;
    tf2x32(0u, 42u, 0u, (uint32_t)next_split, ks0, ks1);
    tf2x32(ks0, ks1, 0u, 0u, kr0, kr1);
    (void)t0; (void)t1;
    __syncthreads();
    for (int e = r0*DIMS + t; e < r1*DIMS; e += 256){
      int cc = e >> 6, d = e & 63;
      float rv = jax_normal_elem(kr0, kr1, (uint32_t)e) * 1e-5f;
      float old = cb[e];
      cb[(curr + cc)*DIMS + d] = old - rv;
      cb[e]                    = old + rv;
    }
    __syncthreads();
    for (int cc = r0 + t; cc < r1; cc += 256){
      float s0 = 0.f, s1 = 0.f;
      for (int d = 0; d < DIMS; d++){
        float v0 = cb[cc*DIMS + d];        s0 += v0*v0;
        float v1 = cb[(curr+cc)*DIMS + d]; s1 += v1*v1;
      }
      cnorm[cc] = s0;
      cnorm[curr + cc] = s1;
    }
  }
}

extern "C" void kernel_launch(void* const* d_in, const int* in_sizes, int n_in,
                              void* d_out, int out_size, void* d_ws, size_t ws_size,
                              hipStream_t stream){
  const float* x = (const float*)d_in[0];
  float* cb = (float*)d_out;
  char* ws = (char*)d_ws;
  unsigned long long* sums0   = (unsigned long long*)(ws + 0);        // 131072 B
  unsigned long long* sums1   = (unsigned long long*)(ws + 131072);   // 131072 B
  unsigned long long* macc    = (unsigned long long*)(ws + 262144);   // 512 B
  unsigned long long* dist0   = (unsigned long long*)(ws + 262656);   // 8 B
  unsigned long long* dist1   = (unsigned long long*)(ws + 262664);   // 8 B
  LbgState* st0               = (LbgState*)(ws + 262672);             // 32 B
  LbgState* st1               = (LbgState*)(ws + 262704);             // 32 B
  unsigned int* nd0           = (unsigned int*)(ws + 262736);         // 1024 B
  unsigned int* nd1           = (unsigned int*)(ws + 263760);         // 1024 B
  float* cnorm                = (float*)(ws + 264784);                // 1024 B
  unsigned char* bidx8        = (unsigned char*)(ws + 265808);        // 131072 B
  unsigned int* mcnt          = (unsigned int*)(ws + 396880);         // 4 B

  unsigned long long* sums[2] = { sums0, sums1 };
  unsigned long long* dac[2]  = { dist0, dist1 };
  LbgState* st[2]             = { st0, st1 };
  unsigned int* nd[2]         = { nd0, nd1 };

  hipMemsetAsync(d_ws, 0, 396884, stream);
  mean_kernel<<<128, 256, 0, stream>>>(x, macc, cb, cnorm, sums0, nd0, dist0, st0, mcnt);

  int g = 0;
  for (int split = 0; split < 8; split++){
    const int curr = 2 << split;
    for (int n = 0; n < 5; n++){
      const int pi = g & 1, po = pi ^ 1;
      switch (curr){
        case 2:   estep_kernel<2>  <<<512,256,0,stream>>>(x,cb,cnorm,bidx8,dac[pi],st[pi]);
                  gather_kernel<2,256>   <<<256, 256,0,stream>>>(x,bidx8,sums[pi],nd[pi],st[pi]); break;
        case 4:   estep_kernel<4>  <<<512,256,0,stream>>>(x,cb,cnorm,bidx8,dac[pi],st[pi]);
                  gather_kernel<4,512>   <<<512, 256,0,stream>>>(x,bidx8,sums[pi],nd[pi],st[pi]); break;
        case 8:   estep_sw<8>    <<<1024,256,0,stream>>>(x,cb,cnorm,bidx8,dac[pi],st[pi]);
                  gather_kernel<8,1024>  <<<1024,256,0,stream>>>(x,bidx8,sums[pi],nd[pi],st[pi]); break;
        case 16:  estep_sw<16>   <<<1024,256,0,stream>>>(x,cb,cnorm,bidx8,dac[pi],st[pi]);
                  gather_kernel<16,2048> <<<2048,256,0,stream>>>(x,bidx8,sums[pi],nd[pi],st[pi]); break;
        case 32:  estep_sw<32>   <<<1024,256,0,stream>>>(x,cb,cnorm,bidx8,dac[pi],st[pi]);
                  gather_kernel<32,2048> <<<2048,256,0,stream>>>(x,bidx8,sums[pi],nd[pi],st[pi]); break;
        case 64:  estep_sw<64>   <<<1024,256,0,stream>>>(x,cb,cnorm,bidx8,dac[pi],st[pi]);
                  gather_kernel<64,2048> <<<2048,256,0,stream>>>(x,bidx8,sums[pi],nd[pi],st[pi]); break;
        case 128: estep_sw<128>  <<<1024,256,0,stream>>>(x,cb,cnorm,bidx8,dac[pi],st[pi]);
                  gather_kernel<128,2048><<<2048,256,0,stream>>>(x,bidx8,sums[pi],nd[pi],st[pi]); break;
        case 256: estep_sw<256>  <<<1024,256,0,stream>>>(x,cb,cnorm,bidx8,dac[pi],st[pi]);
                  gather_kernel<256,2048><<<2048,256,0,stream>>>(x,bidx8,sums[pi],nd[pi],st[pi]); break;
      }
      control_kernel<<<NCB, 256, 0, stream>>>(cb, cnorm,
          sums[pi], sums[po], nd[pi], nd[po], dac[pi], dac[po],
          st[pi], st[po], curr, n, split+1);
      g++;
    }
  }
}